// Round 7
// baseline (102.481 us; speedup 1.0000x reference)
//
#include <hip/hip_runtime.h>
#include <cfloat>

#define NFEAT 256
#define BATCH 4096
#define MTOT  16384
#define NSTRIP 8
#define STRIPW 2048
#define NH 32                 // h-steps per strip, 64 cols each
#define UMARGIN 0.75f

typedef __attribute__((ext_vector_type(8))) short bf16x8;
typedef __attribute__((ext_vector_type(4))) float f32x4;

#define GP(p)   ((const __attribute__((address_space(1))) void*)(p))
#define LDSP(p) ((__attribute__((address_space(3))) void*)(p))

__device__ __forceinline__ unsigned bf16pack(float a, float b) {
    unsigned ua = __float_as_uint(a), ub = __float_as_uint(b);
    unsigned ra = (ua + 0x7fffu + ((ua >> 16) & 1u)) >> 16;
    unsigned rb = (ub + 0x7fffu + ((ub >> 16) & 1u)) >> 16;
    return ra | (rb << 16);
}

// ---------------------------------------------------------------------------
// Prep (fused): fp32->bf16 + squared norm for both w and xb. 1 wave per row.
// ---------------------------------------------------------------------------
__global__ __launch_bounds__(256) void prep_kernel(const float* __restrict__ xb,
                                                   const float* __restrict__ w,
                                                   uint2* __restrict__ Abf,
                                                   uint2* __restrict__ Bbf,
                                                   float* __restrict__ a2,
                                                   float* __restrict__ b2) {
    int gid  = blockIdx.x * blockDim.x + threadIdx.x;
    int row  = gid >> 6;
    int lane = gid & 63;
    const float* src;
    uint2* dst;
    float* nrm;
    if (row < MTOT) {
        src = w + (size_t)row * NFEAT;  dst = Bbf + (size_t)row * 64;  nrm = b2 + row;
    } else {
        int r = row - MTOT;
        src = xb + (size_t)r * NFEAT;   dst = Abf + (size_t)r * 64;    nrm = a2 + r;
    }
    float4 v = ((const float4*)src)[lane];
    dst[lane] = make_uint2(bf16pack(v.x, v.y), bf16pack(v.z, v.w));
    float s = v.x * v.x + v.y * v.y + v.z * v.z + v.w * v.w;
    #pragma unroll
    for (int off = 32; off > 0; off >>= 1) s += __shfl_down(s, off);
    if (lane == 0) *nrm = s;
}

// ---------------------------------------------------------------------------
// Main: barrier-free wave-private producer-consumer MFMA distance GEMM.
// 256 blocks (1/CU), 512 thr = 8 waves (2m x 4c). Wave tile 64 rows x 16 cols.
// A panel (64 x K=256) in registers (pinned). Each wave owns a PRIVATE LDS
// ring: 2 x 8KB buffers holding 16 cols x full K in [kk][g][c] order — the
// staging write and the fragment read are both exactly lane-linear
// (base + kk*1024 + l*16): no swizzle, no bank conflicts, no addr VALU.
// Sync is per-wave s_waitcnt vmcnt(8) ONLY — no s_barrier in the loop, so
// waves phase-drift and hide each other's stalls (round-6 lockstep fix).
// min-dist == max-(dot - b2/2); per-lane top-2 with 5-bit mantissa-packed id.
// ---------------------------------------------------------------------------
__global__ __launch_bounds__(512, 2) void som_mfma_kernel(
        const unsigned short* __restrict__ Abf, const unsigned short* __restrict__ Bbf,
        const float* __restrict__ b2, float* __restrict__ part) {
    __shared__ char smem[139264];   // 8 x (2 x 8KB wave ring) = 128K | b2 8K

    const int t = threadIdx.x, l = t & 63;
    const int wid = t >> 6;
    const int wm = wid >> 2;        // 0..1  row half
    const int wc = wid & 3;         // 0..3  col-16 group
    const int strip = blockIdx.x & 7;          // strip == XCD round-robin
    const int m0 = (blockIdx.x >> 3) * 128;
    const int ns0 = strip * STRIPW;

    // ---- A panel -> registers (frag layout), issued first ----
    const char* gA = (const char*)Abf
                   + (size_t)(m0 + wm * 64 + (l & 15)) * 512 + (l >> 4) * 16;
    bf16x8 afr[4][8];
    #pragma unroll
    for (int m = 0; m < 4; ++m)
        #pragma unroll
        for (int kk = 0; kk < 8; ++kk)
            afr[m][kk] = *(const bf16x8*)(gA + (size_t)m * 16 * 512 + kk * 64);

    // ---- b2 strip stage (1 op, cooperative) ----
    __builtin_amdgcn_global_load_lds(GP((const char*)b2 + (size_t)ns0 * 4 + t * 16),
                                     LDSP(smem + 131072 + t * 16), 16, 0, 0);

    // ---- wave-private B ring prologue: buffers for h=0 (parity 0), h=1 ----
    // op i, lane l loads col (wc*16 + (l&15)), bytes [i*64 + (l>>4)*16 .. +16)
    // into ring byte i*1024 + l*16  ==  [kk=i][g=l>>4][c=l&15] layout.
    char* const reg0 = smem + wid * 16384;
    const char* gBw = (const char*)Bbf
                    + (size_t)(ns0 + wc * 16 + (l & 15)) * 512 + (l >> 4) * 16;
    #pragma unroll
    for (int i = 0; i < 8; ++i)
        __builtin_amdgcn_global_load_lds(GP(gBw + i * 64),
                                         LDSP(reg0 + i * 1024 + l * 16), 16, 0, 0);
    #pragma unroll
    for (int i = 0; i < 8; ++i)
        __builtin_amdgcn_global_load_lds(GP(gBw + 32768 + i * 64),
                                         LDSP(reg0 + 8192 + i * 1024 + l * 16), 16, 0, 0);

    // pin A in registers (asm is the producer -> no remat, no loop vmem)
    #pragma unroll
    for (int m = 0; m < 4; ++m)
        #pragma unroll
        for (int kk = 0; kk < 8; ++kk)
            asm volatile("" : "+v"(afr[m][kk]));

    // b2 visibility: own b2 op drained (A:32 + b2:1 -> vmcnt<=16), then the
    // ONLY cross-wave barrier before the end-merge.
    asm volatile("s_waitcnt vmcnt(16)" ::: "memory");
    __builtin_amdgcn_s_barrier();

    float r0[4][4], r1[4][4];
    #pragma unroll
    for (int m = 0; m < 4; ++m)
        #pragma unroll
        for (int j = 0; j < 4; ++j) { r0[m][j] = -FLT_MAX; r1[m][j] = -FLT_MAX; }

    const char* gBn = gBw + 2 * 32768;   // global src for buffer h+2

    for (int h = 0; h < NH; ++h) {
        // per-wave counted drain: buffer h landed; h+1's 8 ops stay in flight
        if (h < NH - 1) asm volatile("s_waitcnt vmcnt(8)" ::: "memory");
        else            asm volatile("s_waitcnt vmcnt(0)" ::: "memory");

        const char* buf = reg0 + ((h & 1) << 13);
        const float b2c = -0.5f * *(const float*)(smem + 131072
                              + (h * 64 + wc * 16 + (l & 15)) * 4);
        f32x4 acc[4];
        #pragma unroll
        for (int m = 0; m < 4; ++m) acc[m] = (f32x4){b2c, b2c, b2c, b2c};

        #pragma unroll
        for (int kk = 0; kk < 8; ++kk) {
            bf16x8 bf = *(const bf16x8*)(buf + kk * 1024 + l * 16);
            #pragma unroll
            for (int m = 0; m < 4; ++m)
                acc[m] = __builtin_amdgcn_mfma_f32_16x16x32_bf16(afr[m][kk], bf,
                                                                 acc[m], 0, 0, 0);
        }

        // per-lane top-2: pack 5-bit id (= h) into low mantissa bits
        const unsigned idn = (unsigned)h;
        #pragma unroll
        for (int m = 0; m < 4; ++m)
            #pragma unroll
            for (int j = 0; j < 4; ++j) {
                float p = __uint_as_float((__float_as_uint(acc[m][j]) & 0xFFFFFFE0u) | idn);
                float nr1 = __builtin_amdgcn_fmed3f(r0[m][j], r1[m][j], p);
                r0[m][j] = fmaxf(r0[m][j], p);
                r1[m][j] = nr1;
            }

        // refill the just-consumed buffer for h+2 (all reads above retired:
        // the top-2 epilogue depends on acc -> final MFMA -> final ds_read)
        if (h + 2 < NH) {
            char* dst = reg0 + ((h & 1) << 13);
            #pragma unroll
            for (int i = 0; i < 8; ++i)
                __builtin_amdgcn_global_load_lds(GP(gBn + i * 64),
                                                 LDSP(dst + i * 1024 + l * 16), 16, 0, 0);
        }
        gBn += 32768;
    }

    // ---- final merge: re-pack 11-bit id, xor-merge 16 lane-cols, cross-wave
    //      (wc) merge via LDS scratch. Barrier first: waves are unsynced. ----
    __syncthreads();
    float* sm = (float*)smem;           // [128][8]
    #pragma unroll
    for (int m = 0; m < 4; ++m)
        #pragma unroll
        for (int j = 0; j < 4; ++j) {
            unsigned u0 = __float_as_uint(r0[m][j]);
            unsigned u1 = __float_as_uint(r1[m][j]);
            u0 = (u0 & 0xFFFFF800u) | ((u0 & 31u) << 6) | ((unsigned)wc << 4) | (unsigned)(l & 15);
            u1 = (u1 & 0xFFFFF800u) | ((u1 & 31u) << 6) | ((unsigned)wc << 4) | (unsigned)(l & 15);
            float v0 = __uint_as_float(u0), v1 = __uint_as_float(u1);
            #pragma unroll
            for (int off = 1; off < 16; off <<= 1) {
                float o0 = __shfl_xor(v0, off), o1 = __shfl_xor(v1, off);
                float nv1 = fmaxf(fminf(v0, o0), fmaxf(v1, o1));
                v0 = fmaxf(v0, o0);
                v1 = nv1;
            }
            if ((l & 15) == 0) {
                int row_l = wm * 64 + m * 16 + (l >> 4) * 4 + j;
                sm[row_l * 8 + wc * 2 + 0] = v0;
                sm[row_l * 8 + wc * 2 + 1] = v1;
            }
        }
    __syncthreads();
    if (t < 128) {
        float V0 = -FLT_MAX, V1 = -FLT_MAX;
        #pragma unroll
        for (int q = 0; q < 4; ++q) {
            float a0 = sm[t * 8 + q * 2], a1 = sm[t * 8 + q * 2 + 1];
            float nv1 = fmaxf(fminf(V0, a0), fmaxf(V1, a1));
            V0 = fmaxf(V0, a0);
            V1 = nv1;
        }
        ((float2*)part)[(size_t)(m0 + t) * NSTRIP + strip] = make_float2(V0, V1);
    }
}

// ---------------------------------------------------------------------------
// Refine: 1 wave per row over 16 packed entries; exact fp32+sqrt recompute of
// candidates within margin; lexicographic (dist, idx) argmin.
// ---------------------------------------------------------------------------
__global__ __launch_bounds__(256) void refine_kernel(
        const float* __restrict__ xb, const float* __restrict__ w,
        const float* __restrict__ a2, const float* __restrict__ b2,
        const float* __restrict__ part, int* __restrict__ out) {
    const int t = threadIdx.x, l = t & 63;
    const int row = blockIdx.x * 4 + (t >> 6);

    const float* pr = part + (size_t)row * (NSTRIP * 2);
    float v = (l < NSTRIP * 2) ? pr[l] : -FLT_MAX;
    float mx = v;
    #pragma unroll
    for (int off = 1; off < 64; off <<= 1) mx = fmaxf(mx, __shfl_xor(mx, off));
    const float cut = mx - UMARGIN;

    unsigned long long key = ~0ull;
    if (l < NSTRIP * 2 && v >= cut) {
        unsigned b = __float_as_uint(v);
        int c = b & 15, wcb = (b >> 4) & 3, h = (b >> 6) & 31;
        int col = (l >> 1) * STRIPW + h * 64 + wcb * 16 + c;
        const float4* xr = (const float4*)(xb + (size_t)row * NFEAT);
        const float4* wr = (const float4*)(w + (size_t)col * NFEAT);
        float s0 = 0.f, s1 = 0.f, s2 = 0.f, s3 = 0.f;
        #pragma unroll
        for (int k = 0; k < 16; ++k) {
            float4 x0 = xr[4 * k + 0], w0 = wr[4 * k + 0];
            float4 x1 = xr[4 * k + 1], w1 = wr[4 * k + 1];
            float4 x2 = xr[4 * k + 2], w2 = wr[4 * k + 2];
            float4 x3 = xr[4 * k + 3], w3 = wr[4 * k + 3];
            s0 += x0.x * w0.x + x0.y * w0.y + x0.z * w0.z + x0.w * w0.w;
            s1 += x1.x * w1.x + x1.y * w1.y + x1.z * w1.z + x1.w * w1.w;
            s2 += x2.x * w2.x + x2.y * w2.y + x2.z * w2.z + x2.w * w2.w;
            s3 += x3.x * w3.x + x3.y * w3.y + x3.z * w3.z + x3.w * w3.w;
        }
        float dot = (s0 + s1) + (s2 + s3);
        float dd = a2[row] + b2[col] - 2.f * dot;
        float s = sqrtf(fmaxf(dd, 0.f));
        key = ((unsigned long long)__float_as_uint(s) << 32) | (unsigned)col;
    }
    #pragma unroll
    for (int off = 1; off < 64; off <<= 1) {
        unsigned long long o = __shfl_xor(key, off);
        key = o < key ? o : key;
    }
    if (l == 0) {
        int idx = (int)(key & 0xffffffffu);
        out[2 * row]     = idx >> 7;
        out[2 * row + 1] = idx & 127;
    }
}

extern "C" void kernel_launch(void* const* d_in, const int* in_sizes, int n_in,
                              void* d_out, int out_size, void* d_ws, size_t ws_size,
                              hipStream_t stream) {
    const float* xb = (const float*)d_in[0];   // (4096, 256)
    const float* w  = (const float*)d_in[1];   // (16384, 256)
    int* out = (int*)d_out;

    char* ws = (char*)d_ws;
    unsigned short* Abf = (unsigned short*)ws;                 // 2 MB
    unsigned short* Bbf = (unsigned short*)(ws + (2u << 20));  // 8 MB
    float* a2   = (float*)(ws + (10u << 20));                  // 16 KB
    float* b2   = (float*)(ws + (10u << 20) + (64u << 10));    // 64 KB
    float* part = (float*)(ws + (10u << 20) + (128u << 10));   // 256 KB

    prep_kernel<<<((MTOT + BATCH) * 64) / 256, 256, 0, stream>>>(xb, w, (uint2*)Abf,
                                                                 (uint2*)Bbf, a2, b2);
    som_mfma_kernel<<<256, 512, 0, stream>>>(Abf, Bbf, b2, part);
    refine_kernel<<<BATCH / 4, 256, 0, stream>>>(xb, w, a2, b2, part, out);
}

// Round 8
// 76.291 us; speedup vs baseline: 1.3433x; 1.3433x over previous
//
#include <hip/hip_runtime.h>
#include <cfloat>

#define NFEAT 256
#define BATCH 4096
#define MTOT  16384
#define NSTRIP 8
#define STRIPW 2048
#define NH 16                 // h-steps per strip, 128 cols each
#define UMARGIN 0.75f

typedef __attribute__((ext_vector_type(8))) short bf16x8;
typedef __attribute__((ext_vector_type(4))) float f32x4;

#define GP(p)   ((const __attribute__((address_space(1))) void*)(p))
#define LDSP(p) ((__attribute__((address_space(3))) void*)(p))

__device__ __forceinline__ unsigned bf16pack(float a, float b) {
    unsigned ua = __float_as_uint(a), ub = __float_as_uint(b);
    unsigned ra = (ua + 0x7fffu + ((ua >> 16) & 1u)) >> 16;
    unsigned rb = (ub + 0x7fffu + ((ub >> 16) & 1u)) >> 16;
    return ra | (rb << 16);
}

// ---------------------------------------------------------------------------
// Prep (fused): fp32->bf16 + squared norm for both w and xb. 1 wave per row.
// ---------------------------------------------------------------------------
__global__ __launch_bounds__(256) void prep_kernel(const float* __restrict__ xb,
                                                   const float* __restrict__ w,
                                                   uint2* __restrict__ Abf,
                                                   uint2* __restrict__ Bbf,
                                                   float* __restrict__ a2,
                                                   float* __restrict__ b2) {
    int gid  = blockIdx.x * blockDim.x + threadIdx.x;
    int row  = gid >> 6;
    int lane = gid & 63;
    const float* src;
    uint2* dst;
    float* nrm;
    if (row < MTOT) {
        src = w + (size_t)row * NFEAT;  dst = Bbf + (size_t)row * 64;  nrm = b2 + row;
    } else {
        int r = row - MTOT;
        src = xb + (size_t)r * NFEAT;   dst = Abf + (size_t)r * 64;    nrm = a2 + r;
    }
    float4 v = ((const float4*)src)[lane];
    dst[lane] = make_uint2(bf16pack(v.x, v.y), bf16pack(v.z, v.w));
    float s = v.x * v.x + v.y * v.y + v.z * v.z + v.w * v.w;
    #pragma unroll
    for (int off = 32; off > 0; off >>= 1) s += __shfl_down(s, off);
    if (lane == 0) *nrm = s;
}

// ---------------------------------------------------------------------------
// Main: split-K sub-phase pipeline. 256 blocks (1/CU), 512 thr = 8 waves
// (4m x 2c), wave tile 32 rows x 64 cols. A panel = afr[2][8] = 64 TRUE VGPRs
// (small enough to avoid AGPR shuttling — rounds 5-7 failure). B double-buffer
// 2 x 64 KB; LDS layout [K-half 32K][col*256B] so staging ops 0-3 = K-half0 of
// all 128 cols. Per h: two sub-phases, each {vmcnt(counted) -> barrier ->
// MFMA cluster (setprio) -> barrier -> refill freed half}. vmcnt >= 8 except
// the tail. Read swizzle ^((col&15)<<4) -> 4-way max; staging lane-linear
// with inverse swizzle on the global source (T21 both-sides rule).
// min-dist == max-(dot - b2/2); per-lane top-2 with 6-bit mantissa-packed id.
// ---------------------------------------------------------------------------
__global__ __launch_bounds__(512, 2) void som_mfma_kernel(
        const unsigned short* __restrict__ Abf, const unsigned short* __restrict__ Bbf,
        const float* __restrict__ b2, float* __restrict__ part) {
    __shared__ char smem[139264];   // buf0 64K | buf1 64K | b2 strip 8K

    const int t = threadIdx.x, l = t & 63;
    const int wid = t >> 6;
    const int wm = wid >> 1;        // 0..3 row 32-group
    const int wc = wid & 1;         // 0..1 col 64-half
    const int strip = blockIdx.x & 7;          // strip == XCD round-robin
    const int m0 = (blockIdx.x >> 3) * 128;
    const int ns0 = strip * STRIPW;

    // ---- A panel -> 64 true VGPRs, loaded + settled in prologue ----
    const char* gA = (const char*)Abf
                   + (size_t)(m0 + wm * 32 + (l & 15)) * 512 + (l >> 4) * 16;
    bf16x8 afr[2][8];
    #pragma unroll
    for (int mf = 0; mf < 2; ++mf)
        #pragma unroll
        for (int kk = 0; kk < 8; ++kk)
            afr[mf][kk] = *(const bf16x8*)(gA + (size_t)mf * 16 * 512 + kk * 64);
    #pragma unroll
    for (int mf = 0; mf < 2; ++mf)
        #pragma unroll
        for (int kk = 0; kk < 8; ++kk)
            asm volatile("" : "+v"(afr[mf][kk]));   // settle BEFORE staging issues

    // ---- staging geometry ----
    // op(sub,r): thread t covers col = sub*32 + (t>>4), region r (K-half),
    // in-col byte (t&15)*16, source pre-swizzled by ((col&15)<<4).
    const char* gB = (const char*)Bbf + (size_t)(ns0 + (t >> 4)) * 512
                   + (((t & 15) * 16) ^ (((t >> 4) & 15) << 4));
    // src(sub,r,h) = gB + h*65536 + sub*16384 + r*256
    // dst(sub,r,p) = smem + p*65536 + r*32768 + sub*8192 + t*16
#define STAGE(p, hh, r) {                                                        \
        const char* s_ = gB + (size_t)(hh) * 65536 + (r) * 256;                  \
        char* d_ = smem + (p) * 65536 + (r) * 32768 + t * 16;                    \
        __builtin_amdgcn_global_load_lds(GP(s_),         LDSP(d_),         16,0,0); \
        __builtin_amdgcn_global_load_lds(GP(s_ + 16384), LDSP(d_ + 8192),  16,0,0); \
        __builtin_amdgcn_global_load_lds(GP(s_ + 32768), LDSP(d_ + 16384), 16,0,0); \
        __builtin_amdgcn_global_load_lds(GP(s_ + 49152), LDSP(d_ + 24576), 16,0,0); }

    // b2 strip + prologue staging: buf0{h0,h1} for h=0, buf1{h0,h1} for h=1
    __builtin_amdgcn_global_load_lds(GP((const char*)b2 + (size_t)ns0 * 4 + t * 16),
                                     LDSP(smem + 131072 + t * 16), 16, 0, 0);
    STAGE(0, 0, 0) STAGE(0, 0, 1) STAGE(1, 1, 0) STAGE(1, 1, 1)

    asm volatile("s_waitcnt vmcnt(16)" ::: "memory");   // b2 landed; 16 in flight
    __builtin_amdgcn_s_barrier();

    float r0[2][4], r1[2][4];
    #pragma unroll
    for (int mf = 0; mf < 2; ++mf)
        #pragma unroll
        for (int j = 0; j < 4; ++j) { r0[mf][j] = -FLT_MAX; r1[mf][j] = -FLT_MAX; }

    const int rswz = (l & 15) << 4;
    const int cbyte0 = (wc * 64 + (l & 15)) * 256;      // nf adds 16*256

    for (int h = 0; h < NH; ++h) {
        const char* buf = smem + ((h & 1) << 16);

        float b2r[4];
        #pragma unroll
        for (int nf = 0; nf < 4; ++nf)
            b2r[nf] = -0.5f * *(const float*)(smem + 131072
                          + (h * 128 + wc * 64 + nf * 16 + (l & 15)) * 4);
        f32x4 acc[2][4];
        #pragma unroll
        for (int mf = 0; mf < 2; ++mf)
            #pragma unroll
            for (int nf = 0; nf < 4; ++nf)
                acc[mf][nf] = (f32x4){b2r[nf], b2r[nf], b2r[nf], b2r[nf]};

        // ---------- sub-phase 0: K 0..127 ----------
        if (h < NH - 1) asm volatile("s_waitcnt vmcnt(12)" ::: "memory");
        else            asm volatile("s_waitcnt vmcnt(4)"  ::: "memory");
        __builtin_amdgcn_s_barrier();
        asm volatile("" ::: "memory");
        __builtin_amdgcn_s_setprio(1);
        #pragma unroll
        for (int kk = 0; kk < 4; ++kk) {
            const int ko = (kk * 64 + (l >> 4) * 16) ^ rswz;
            bf16x8 bfr[4];
            #pragma unroll
            for (int nf = 0; nf < 4; ++nf)
                bfr[nf] = *(const bf16x8*)(buf + cbyte0 + nf * 4096 + ko);
            #pragma unroll
            for (int mf = 0; mf < 2; ++mf)
                #pragma unroll
                for (int nf = 0; nf < 4; ++nf)
                    acc[mf][nf] = __builtin_amdgcn_mfma_f32_16x16x32_bf16(
                        afr[mf][kk], bfr[nf], acc[mf][nf], 0, 0, 0);
        }
        __builtin_amdgcn_s_setprio(0);
        asm volatile("" ::: "memory");
        __builtin_amdgcn_s_barrier();
        asm volatile("" ::: "memory");
        if (h + 2 < NH) STAGE(h & 1, h + 2, 0)

        // ---------- sub-phase 1: K 128..255 ----------
        if      (h < NH - 2) asm volatile("s_waitcnt vmcnt(12)" ::: "memory");
        else if (h == NH - 2) asm volatile("s_waitcnt vmcnt(8)" ::: "memory");
        else                  asm volatile("s_waitcnt vmcnt(0)" ::: "memory");
        __builtin_amdgcn_s_barrier();
        asm volatile("" ::: "memory");
        __builtin_amdgcn_s_setprio(1);
        #pragma unroll
        for (int kk = 0; kk < 4; ++kk) {
            const int ko = (kk * 64 + (l >> 4) * 16) ^ rswz;
            bf16x8 bfr[4];
            #pragma unroll
            for (int nf = 0; nf < 4; ++nf)
                bfr[nf] = *(const bf16x8*)(buf + 32768 + cbyte0 + nf * 4096 + ko);
            #pragma unroll
            for (int mf = 0; mf < 2; ++mf)
                #pragma unroll
                for (int nf = 0; nf < 4; ++nf)
                    acc[mf][nf] = __builtin_amdgcn_mfma_f32_16x16x32_bf16(
                        afr[mf][kk + 4], bfr[nf], acc[mf][nf], 0, 0, 0);
        }
        __builtin_amdgcn_s_setprio(0);
        asm volatile("" ::: "memory");
        __builtin_amdgcn_s_barrier();
        asm volatile("" ::: "memory");
        if (h + 2 < NH) STAGE(h & 1, h + 2, 1)

        // ---------- top-2 fold: id = h*4+nf (6 bits) ----------
        #pragma unroll
        for (int nf = 0; nf < 4; ++nf) {
            const unsigned idn = (unsigned)(h * 4 + nf);
            #pragma unroll
            for (int mf = 0; mf < 2; ++mf)
                #pragma unroll
                for (int j = 0; j < 4; ++j) {
                    float p = __uint_as_float((__float_as_uint(acc[mf][nf][j]) & 0xFFFFFFC0u) | idn);
                    float nr1 = __builtin_amdgcn_fmed3f(r0[mf][j], r1[mf][j], p);
                    r0[mf][j] = fmaxf(r0[mf][j], p);
                    r1[mf][j] = nr1;
                }
        }
    }

    // ---- final merge: re-pack 11-bit id, xor-merge 16 lane-cols, cross-wave
    //      (wc) merge via LDS scratch, store per-row top-2 ----
    __syncthreads();
    float* sm = (float*)smem;           // [128][4]
    #pragma unroll
    for (int mf = 0; mf < 2; ++mf)
        #pragma unroll
        for (int j = 0; j < 4; ++j) {
            unsigned u0 = __float_as_uint(r0[mf][j]);
            unsigned u1 = __float_as_uint(r1[mf][j]);
            u0 = (u0 & 0xFFFFF800u) | ((u0 & 63u) << 5) | ((unsigned)wc << 4) | (unsigned)(l & 15);
            u1 = (u1 & 0xFFFFF800u) | ((u1 & 63u) << 5) | ((unsigned)wc << 4) | (unsigned)(l & 15);
            float v0 = __uint_as_float(u0), v1 = __uint_as_float(u1);
            #pragma unroll
            for (int off = 1; off < 16; off <<= 1) {
                float o0 = __shfl_xor(v0, off), o1 = __shfl_xor(v1, off);
                float nv1 = fmaxf(fminf(v0, o0), fmaxf(v1, o1));
                v0 = fmaxf(v0, o0);
                v1 = nv1;
            }
            if ((l & 15) == 0) {
                int row_l = wm * 32 + mf * 16 + (l >> 4) * 4 + j;
                sm[row_l * 4 + wc * 2 + 0] = v0;
                sm[row_l * 4 + wc * 2 + 1] = v1;
            }
        }
    __syncthreads();
    if (t < 128) {
        float a0 = sm[t * 4 + 0], a1 = sm[t * 4 + 1];
        float c0 = sm[t * 4 + 2], c1 = sm[t * 4 + 3];
        float V0 = fmaxf(a0, c0);
        float V1 = fmaxf(fminf(a0, c0), fmaxf(a1, c1));
        ((float2*)part)[(size_t)(m0 + t) * NSTRIP + strip] = make_float2(V0, V1);
    }
#undef STAGE
}

// ---------------------------------------------------------------------------
// Refine: 1 wave per row over 16 packed entries; exact fp32+sqrt recompute of
// candidates within margin; lexicographic (dist, idx) argmin.
// ---------------------------------------------------------------------------
__global__ __launch_bounds__(256) void refine_kernel(
        const float* __restrict__ xb, const float* __restrict__ w,
        const float* __restrict__ a2, const float* __restrict__ b2,
        const float* __restrict__ part, int* __restrict__ out) {
    const int t = threadIdx.x, l = t & 63;
    const int row = blockIdx.x * 4 + (t >> 6);

    const float* pr = part + (size_t)row * (NSTRIP * 2);
    float v = (l < NSTRIP * 2) ? pr[l] : -FLT_MAX;
    float mx = v;
    #pragma unroll
    for (int off = 1; off < 64; off <<= 1) mx = fmaxf(mx, __shfl_xor(mx, off));
    const float cut = mx - UMARGIN;

    unsigned long long key = ~0ull;
    if (l < NSTRIP * 2 && v >= cut) {
        unsigned b = __float_as_uint(v);
        int lane4 = b & 15, wcb = (b >> 4) & 1, in6 = (b >> 5) & 63;
        int col = (l >> 1) * STRIPW + (in6 >> 2) * 128 + wcb * 64
                + (in6 & 3) * 16 + lane4;
        const float4* xr = (const float4*)(xb + (size_t)row * NFEAT);
        const float4* wr = (const float4*)(w + (size_t)col * NFEAT);
        float s0 = 0.f, s1 = 0.f, s2 = 0.f, s3 = 0.f;
        #pragma unroll
        for (int k = 0; k < 16; ++k) {
            float4 x0 = xr[4 * k + 0], w0 = wr[4 * k + 0];
            float4 x1 = xr[4 * k + 1], w1 = wr[4 * k + 1];
            float4 x2 = xr[4 * k + 2], w2 = wr[4 * k + 2];
            float4 x3 = xr[4 * k + 3], w3 = wr[4 * k + 3];
            s0 += x0.x * w0.x + x0.y * w0.y + x0.z * w0.z + x0.w * w0.w;
            s1 += x1.x * w1.x + x1.y * w1.y + x1.z * w1.z + x1.w * w1.w;
            s2 += x2.x * w2.x + x2.y * w2.y + x2.z * w2.z + x2.w * w2.w;
            s3 += x3.x * w3.x + x3.y * w3.y + x3.z * w3.z + x3.w * w3.w;
        }
        float dot = (s0 + s1) + (s2 + s3);
        float dd = a2[row] + b2[col] - 2.f * dot;
        float s = sqrtf(fmaxf(dd, 0.f));
        key = ((unsigned long long)__float_as_uint(s) << 32) | (unsigned)col;
    }
    #pragma unroll
    for (int off = 1; off < 64; off <<= 1) {
        unsigned long long o = __shfl_xor(key, off);
        key = o < key ? o : key;
    }
    if (l == 0) {
        int idx = (int)(key & 0xffffffffu);
        out[2 * row]     = idx >> 7;
        out[2 * row + 1] = idx & 127;
    }
}

extern "C" void kernel_launch(void* const* d_in, const int* in_sizes, int n_in,
                              void* d_out, int out_size, void* d_ws, size_t ws_size,
                              hipStream_t stream) {
    const float* xb = (const float*)d_in[0];   // (4096, 256)
    const float* w  = (const float*)d_in[1];   // (16384, 256)
    int* out = (int*)d_out;

    char* ws = (char*)d_ws;
    unsigned short* Abf = (unsigned short*)ws;                 // 2 MB
    unsigned short* Bbf = (unsigned short*)(ws + (2u << 20));  // 8 MB
    float* a2   = (float*)(ws + (10u << 20));                  // 16 KB
    float* b2   = (float*)(ws + (10u << 20) + (64u << 10));    // 64 KB
    float* part = (float*)(ws + (10u << 20) + (128u << 10));   // 512 KB

    prep_kernel<<<((MTOT + BATCH) * 64) / 256, 256, 0, stream>>>(xb, w, (uint2*)Abf,
                                                                 (uint2*)Bbf, a2, b2);
    som_mfma_kernel<<<256, 512, 0, stream>>>(Abf, Bbf, b2, part);
    refine_kernel<<<BATCH / 4, 256, 0, stream>>>(xb, w, a2, b2, part, out);
}

// Round 9
// 72.466 us; speedup vs baseline: 1.4142x; 1.0528x over previous
//
#include <hip/hip_runtime.h>
#include <cfloat>

#define NFEAT 256
#define BATCH 4096
#define MTOT  16384
#define NSTRIP 16
#define STRIPW 1024
#define NH 16                 // h-steps per strip, 64 cols each, full K
#define UMARGIN 0.75f

typedef __attribute__((ext_vector_type(8))) short bf16x8;
typedef __attribute__((ext_vector_type(4))) float f32x4;

#define GP(p)   ((const __attribute__((address_space(1))) void*)(p))
#define LDSP(p) ((__attribute__((address_space(3))) void*)(p))

__device__ __forceinline__ unsigned bf16pack(float a, float b) {
    unsigned ua = __float_as_uint(a), ub = __float_as_uint(b);
    unsigned ra = (ua + 0x7fffu + ((ua >> 16) & 1u)) >> 16;
    unsigned rb = (ub + 0x7fffu + ((ub >> 16) & 1u)) >> 16;
    return ra | (rb << 16);
}

// ---------------------------------------------------------------------------
// Prep (fused): fp32->bf16 + squared norm for both w and xb. 1 wave per row.
// ---------------------------------------------------------------------------
__global__ __launch_bounds__(256) void prep_kernel(const float* __restrict__ xb,
                                                   const float* __restrict__ w,
                                                   uint2* __restrict__ Abf,
                                                   uint2* __restrict__ Bbf,
                                                   float* __restrict__ a2,
                                                   float* __restrict__ b2) {
    int gid  = blockIdx.x * blockDim.x + threadIdx.x;
    int row  = gid >> 6;
    int lane = gid & 63;
    const float* src;
    uint2* dst;
    float* nrm;
    if (row < MTOT) {
        src = w + (size_t)row * NFEAT;  dst = Bbf + (size_t)row * 64;  nrm = b2 + row;
    } else {
        int r = row - MTOT;
        src = xb + (size_t)r * NFEAT;   dst = Abf + (size_t)r * 64;    nrm = a2 + r;
    }
    float4 v = ((const float4*)src)[lane];
    dst[lane] = make_uint2(bf16pack(v.x, v.y), bf16pack(v.z, v.w));
    float s = v.x * v.x + v.y * v.y + v.z * v.z + v.w * v.w;
    #pragma unroll
    for (int off = 32; off > 0; off >>= 1) s += __shfl_down(s, off);
    if (lane == 0) *nrm = s;
}

// ---------------------------------------------------------------------------
// Main: 2-blocks/CU MFMA distance GEMM (round-3 occupancy + the good parts of
// rounds 5-8). Grid 512 = 32 m-tiles x 16 strips; block = 256 thr = 4 waves
// (2m x 2c); wave tile 64 rows x 32 cols; A panel afr[4][8] in regs/AGPRs.
// LDS = B dbuf 2 x 32 KB (64 cols full-K) + b2 4 KB = 68 KB -> 2 blocks/CU:
// cross-block wave overlap fills barrier/vmcnt stalls (the rounds-4..8 wall).
// Per h: vmcnt(8) -> barrier -> 16 ds_read + 64 MFMA (setprio) -> barrier ->
// stage h+2 -> top-2 fold. Read swizzle ^((col&15)<<4), inverse pre-applied
// to the staging source (T21): conflict-free on both sides.
// min-dist == max-(dot - b2/2); per-lane top-2 with 5-bit mantissa-packed id.
// ---------------------------------------------------------------------------
__global__ __launch_bounds__(256, 2) void som_mfma_kernel(
        const unsigned short* __restrict__ Abf, const unsigned short* __restrict__ Bbf,
        const float* __restrict__ b2, float* __restrict__ part) {
    __shared__ char smem[69632];    // P0 32K | P1 32K | b2 strip 4K

    const int t = threadIdx.x, l = t & 63;
    const int wid = t >> 6;
    const int wm = wid >> 1;        // 0..1 row 64-half
    const int wc = wid & 1;         // 0..1 col 32-half
    // 512 blocks: x = XCD slot (0..7), y: m-tile (0..31) + strip parity
    const int x = blockIdx.x & 7, y = blockIdx.x >> 3;
    const int strip = x * 2 + (y >> 5);        // 2 strips per XCD (L2-resident)
    const int m0 = (y & 31) * 128;
    const int ns0 = strip * STRIPW;

    // ---- A panel -> 128 regs (frag layout), loaded + pinned up front ----
    const char* gA = (const char*)Abf
                   + (size_t)(m0 + wm * 64 + (l & 15)) * 512 + (l >> 4) * 16;
    bf16x8 afr[4][8];
    #pragma unroll
    for (int m = 0; m < 4; ++m)
        #pragma unroll
        for (int kk = 0; kk < 8; ++kk)
            afr[m][kk] = *(const bf16x8*)(gA + (size_t)m * 16 * 512 + kk * 64);
    #pragma unroll
    for (int m = 0; m < 4; ++m)
        #pragma unroll
        for (int kk = 0; kk < 8; ++kk)
            asm volatile("" : "+v"(afr[m][kk]));

    // ---- staging geometry (chunk = 64 cols x 512 B = 32 KB, 8 ops/thread) --
    // op i: col = i*8 + (t>>5), in-col byte (t&31)*16 pre-swizzled by
    // ((col&15)<<4) = ((t>>5)<<4) ^ ((i&1)<<7).
    const int sbyte = ((t & 31) * 16) ^ ((t >> 5) << 4);
    const char* gBs0 = (const char*)Bbf + (size_t)ns0 * 512
                     + (size_t)(t >> 5) * 512 + sbyte;
    const char* gBs1 = (const char*)Bbf + (size_t)ns0 * 512
                     + (size_t)(t >> 5) * 512 + (sbyte ^ 128);
#define STAGE(p, hh) {                                                           \
        _Pragma("unroll")                                                        \
        for (int i_ = 0; i_ < 8; ++i_) {                                         \
            const char* s_ = ((i_ & 1) ? gBs1 : gBs0)                            \
                           + (size_t)(hh) * 32768 + i_ * 4096;                   \
            __builtin_amdgcn_global_load_lds(GP(s_),                             \
                LDSP(smem + (p) * 32768 + i_ * 4096 + t * 16), 16, 0, 0);        \
        } }

    // b2 strip (1 op) + prologue chunks 0 -> P0, 1 -> P1
    __builtin_amdgcn_global_load_lds(GP((const char*)b2 + (size_t)ns0 * 4 + t * 16),
                                     LDSP(smem + 65536 + t * 16), 16, 0, 0);
    STAGE(0, 0)
    STAGE(1, 1)

    float r0[4][4], r1[4][4];
    #pragma unroll
    for (int m = 0; m < 4; ++m)
        #pragma unroll
        for (int j = 0; j < 4; ++j) { r0[m][j] = -FLT_MAX; r1[m][j] = -FLT_MAX; }

    const int rswz = (l & 15) << 4;
    const int cbyte0 = (wc * 32 + (l & 15)) * 512;      // nf adds 16*512

    for (int h = 0; h < NH; ++h) {
        if (h < NH - 1) asm volatile("s_waitcnt vmcnt(8)" ::: "memory");
        else            asm volatile("s_waitcnt vmcnt(0)" ::: "memory");
        __builtin_amdgcn_s_barrier();
        asm volatile("" ::: "memory");

        const char* buf = smem + ((h & 1) << 15);
        const int c0 = h * 64 + wc * 32 + (l & 15);
        const float b20 = -0.5f * *(const float*)(smem + 65536 + c0 * 4);
        const float b21 = -0.5f * *(const float*)(smem + 65536 + c0 * 4 + 64);

        f32x4 acc[4][2];
        #pragma unroll
        for (int m = 0; m < 4; ++m) {
            acc[m][0] = (f32x4){b20, b20, b20, b20};
            acc[m][1] = (f32x4){b21, b21, b21, b21};
        }

        __builtin_amdgcn_s_setprio(1);
        #pragma unroll
        for (int kk = 0; kk < 8; ++kk) {
            const int ko = (kk * 64 + (l >> 4) * 16) ^ rswz;
            bf16x8 bf0 = *(const bf16x8*)(buf + cbyte0 + ko);
            bf16x8 bf1 = *(const bf16x8*)(buf + cbyte0 + 8192 + ko);
            #pragma unroll
            for (int m = 0; m < 4; ++m) {
                acc[m][0] = __builtin_amdgcn_mfma_f32_16x16x32_bf16(afr[m][kk], bf0, acc[m][0], 0, 0, 0);
                acc[m][1] = __builtin_amdgcn_mfma_f32_16x16x32_bf16(afr[m][kk], bf1, acc[m][1], 0, 0, 0);
            }
        }
        __builtin_amdgcn_s_setprio(0);

        asm volatile("" ::: "memory");
        __builtin_amdgcn_s_barrier();       // all waves done reading buf(h&1)
        asm volatile("" ::: "memory");
        if (h + 2 < NH) STAGE(h & 1, h + 2)

        // ---- top-2 fold: 5-bit id (h*2 + nf) in low mantissa bits ----
        #pragma unroll
        for (int nf = 0; nf < 2; ++nf) {
            const unsigned idn = (unsigned)(h * 2 + nf);
            #pragma unroll
            for (int m = 0; m < 4; ++m)
                #pragma unroll
                for (int j = 0; j < 4; ++j) {
                    float p = __uint_as_float((__float_as_uint(acc[m][nf][j]) & 0xFFFFFFE0u) | idn);
                    float nr1 = __builtin_amdgcn_fmed3f(r0[m][j], r1[m][j], p);
                    r0[m][j] = fmaxf(r0[m][j], p);
                    r1[m][j] = nr1;
                }
        }
    }

    // ---- final merge: re-pack 10-bit id, xor-merge 16 lane-cols, cross-wave
    //      (wc) merge via LDS scratch, store per-row top-2 ----
    float* sm = (float*)smem;           // [128][4] (P0 region, dead)
    #pragma unroll
    for (int m = 0; m < 4; ++m)
        #pragma unroll
        for (int j = 0; j < 4; ++j) {
            unsigned u0 = __float_as_uint(r0[m][j]);
            unsigned u1 = __float_as_uint(r1[m][j]);
            u0 = (u0 & 0xFFFFFC00u) | ((u0 & 31u) << 5) | ((unsigned)wc << 4) | (unsigned)(l & 15);
            u1 = (u1 & 0xFFFFFC00u) | ((u1 & 31u) << 5) | ((unsigned)wc << 4) | (unsigned)(l & 15);
            float v0 = __uint_as_float(u0), v1 = __uint_as_float(u1);
            #pragma unroll
            for (int off = 1; off < 16; off <<= 1) {
                float o0 = __shfl_xor(v0, off), o1 = __shfl_xor(v1, off);
                float nv1 = fmaxf(fminf(v0, o0), fmaxf(v1, o1));
                v0 = fmaxf(v0, o0);
                v1 = nv1;
            }
            if ((l & 15) == 0) {
                int row_l = wm * 64 + m * 16 + (l >> 4) * 4 + j;
                sm[row_l * 4 + wc * 2 + 0] = v0;
                sm[row_l * 4 + wc * 2 + 1] = v1;
            }
        }
    __syncthreads();
    if (t < 128) {
        float a0 = sm[t * 4 + 0], a1 = sm[t * 4 + 1];
        float c0 = sm[t * 4 + 2], c1 = sm[t * 4 + 3];
        float V0 = fmaxf(a0, c0);
        float V1 = fmaxf(fminf(a0, c0), fmaxf(a1, c1));
        ((float2*)part)[(size_t)(m0 + t) * NSTRIP + strip] = make_float2(V0, V1);
    }
#undef STAGE
}

// ---------------------------------------------------------------------------
// Refine: 1 wave per row over 32 packed entries; exact fp32+sqrt recompute of
// candidates within margin; lexicographic (dist, idx) argmin.
// ---------------------------------------------------------------------------
__global__ __launch_bounds__(256) void refine_kernel(
        const float* __restrict__ xb, const float* __restrict__ w,
        const float* __restrict__ a2, const float* __restrict__ b2,
        const float* __restrict__ part, int* __restrict__ out) {
    const int t = threadIdx.x, l = t & 63;
    const int row = blockIdx.x * 4 + (t >> 6);

    const float* pr = part + (size_t)row * (NSTRIP * 2);
    float v = (l < NSTRIP * 2) ? pr[l] : -FLT_MAX;
    float mx = v;
    #pragma unroll
    for (int off = 1; off < 64; off <<= 1) mx = fmaxf(mx, __shfl_xor(mx, off));
    const float cut = mx - UMARGIN;

    unsigned long long key = ~0ull;
    if (l < NSTRIP * 2 && v >= cut) {
        unsigned b = __float_as_uint(v);
        int lane4 = b & 15, wcb = (b >> 4) & 1, id5 = (b >> 5) & 31;
        int col = (l >> 1) * STRIPW + (id5 >> 1) * 64 + wcb * 32
                + (id5 & 1) * 16 + lane4;
        const float4* xr = (const float4*)(xb + (size_t)row * NFEAT);
        const float4* wr = (const float4*)(w + (size_t)col * NFEAT);
        float s0 = 0.f, s1 = 0.f, s2 = 0.f, s3 = 0.f;
        #pragma unroll
        for (int k = 0; k < 16; ++k) {
            float4 x0 = xr[4 * k + 0], w0 = wr[4 * k + 0];
            float4 x1 = xr[4 * k + 1], w1 = wr[4 * k + 1];
            float4 x2 = xr[4 * k + 2], w2 = wr[4 * k + 2];
            float4 x3 = xr[4 * k + 3], w3 = wr[4 * k + 3];
            s0 += x0.x * w0.x + x0.y * w0.y + x0.z * w0.z + x0.w * w0.w;
            s1 += x1.x * w1.x + x1.y * w1.y + x1.z * w1.z + x1.w * w1.w;
            s2 += x2.x * w2.x + x2.y * w2.y + x2.z * w2.z + x2.w * w2.w;
            s3 += x3.x * w3.x + x3.y * w3.y + x3.z * w3.z + x3.w * w3.w;
        }
        float dot = (s0 + s1) + (s2 + s3);
        float dd = a2[row] + b2[col] - 2.f * dot;
        float s = sqrtf(fmaxf(dd, 0.f));
        key = ((unsigned long long)__float_as_uint(s) << 32) | (unsigned)col;
    }
    #pragma unroll
    for (int off = 1; off < 64; off <<= 1) {
        unsigned long long o = __shfl_xor(key, off);
        key = o < key ? o : key;
    }
    if (l == 0) {
        int idx = (int)(key & 0xffffffffu);
        out[2 * row]     = idx >> 7;
        out[2 * row + 1] = idx & 127;
    }
}

extern "C" void kernel_launch(void* const* d_in, const int* in_sizes, int n_in,
                              void* d_out, int out_size, void* d_ws, size_t ws_size,
                              hipStream_t stream) {
    const float* xb = (const float*)d_in[0];   // (4096, 256)
    const float* w  = (const float*)d_in[1];   // (16384, 256)
    int* out = (int*)d_out;

    char* ws = (char*)d_ws;
    unsigned short* Abf = (unsigned short*)ws;                 // 2 MB
    unsigned short* Bbf = (unsigned short*)(ws + (2u << 20));  // 8 MB
    float* a2   = (float*)(ws + (10u << 20));                  // 16 KB
    float* b2   = (float*)(ws + (10u << 20) + (64u << 10));    // 64 KB
    float* part = (float*)(ws + (10u << 20) + (128u << 10));   // 512 KB

    prep_kernel<<<((MTOT + BATCH) * 64) / 256, 256, 0, stream>>>(xb, w, (uint2*)Abf,
                                                                 (uint2*)Bbf, a2, b2);
    som_mfma_kernel<<<512, 256, 0, stream>>>(Abf, Bbf, b2, part);
    refine_kernel<<<BATCH / 4, 256, 0, stream>>>(xb, w, a2, b2, part, out);
}